// Round 5
// baseline (116.224 us; speedup 1.0000x reference)
//
#include <hip/hip_runtime.h>

// Problem constants (reference: B,H,I,E = 16,16,512,512)
#define B_ 16
#define H_ 16
#define I_ 512
#define E_ 512

// Algebraic collapse (verified earlier rounds, absmax <= 0.25):
//   softmax(axis=2) followed by sum(axis=2) makes attention exact identity on V:
//   emb[b,h,e] = sum_i x[b,i,e] * W_v[h,i,e];  out = emb @ mlp_w^T + mlp_b.
//
// Round-1: cooperative grid.sync ~50us each on 8-XCD gfx950 -> dead.
// Round-2: device-scope fences serialize (L2 wb/inv per XCD) -> dead.
// Round-4: MLP LDS-swizzle rebuild = neutral; fill-time noise is +-2-3us,
//   so only >=5us structural changes are measurable.
// This round: k_emb_part rebuilt for SINGLE-READ of inputs. Old version's
// 2x2 b/h-half decomposition read x and W_v twice each (64 MB logical, and
// the 256 MB workspace poison fill evicts L3 between iterations -> HBM).
// New: each block covers all 16 b x all 16 h (waves own quadrants) x 64 e
// x 32 i, staging inputs through LDS once (32 MB total). Waves no longer
// split i -> no cross-wave LDS reduce; partials store straight from regs.

#define NSLICE 16   // i-slices for emb partials (32 i's each)
#define KSPLIT 8    // k-split for mlp partials (64 k's each)

// ---------------------------------------------------------------------------
// Kernel 1: partial emb, single-read shared-LDS version.
// Grid (E/64=8, NSLICE=16) = 128 blocks, 256 threads.
// Block: 16b x 16h x 64e (lane=e), slice of 32 i's in 4 LDS chunks of 8.
// Wave quadrants: wave w -> b-half (w&1), h-half (w>>1); 8x8 acc per lane.
// LDS 64 KB: xs[8][16][64] + ws[8][16][64].
//   staging: b128 writes, 1024 B/instr spread evenly over all 32 banks;
//   inner reads: 64-lane stride-1 b32 (2 lanes/bank = free).
// Per-i LDS demand 16 KB/block = 64 CU-cycles < 128 fma CU-cycles -> the
// inner loop is compute-bound. Global reads 256 KB/block x 128 = 32 MB.
// ---------------------------------------------------------------------------
__global__ __launch_bounds__(256) void k_emb_part(const float* __restrict__ x,
                                                  const float* __restrict__ Wv,
                                                  float* __restrict__ part) {
    const int etile = blockIdx.x;         // 0..7
    const int slice = blockIdx.y;         // 0..15
    const int t     = (int)threadIdx.x;
    const int lane  = t & 63;
    const int wave  = t >> 6;             // 0..3
    const int e     = etile * 64 + lane;
    const int b0    = (wave & 1) * 8;
    const int h0    = (wave >> 1) * 8;

    __shared__ float xs[8][16][64];       // [ii][b][e]  32 KB
    __shared__ float ws[8][16][64];       // [ii][h][e]  32 KB

    float acc[8][8];
#pragma unroll
    for (int bi = 0; bi < 8; ++bi)
#pragma unroll
        for (int hj = 0; hj < 8; ++hj) acc[bi][hj] = 0.0f;

    const int ibase0 = slice * 32;

    for (int chunk = 0; chunk < 4; ++chunk) {
        const int ib = ibase0 + chunk * 8;
        if (chunk) __syncthreads();       // protect LDS reuse across chunks
        // stage: xs and ws are each 2048 float4 -> 8 per thread.
        // f -> (ii = f>>8, b = (f>>4)&15, eq = f&15); 16 consecutive threads
        // read 64 contiguous floats of one (b, i) row -> coalesced.
#pragma unroll
        for (int it2 = 0; it2 < 8; ++it2) {
            const int f  = t + it2 * 256;
            const int ii = f >> 8;
            const int bb = (f >> 4) & 15;
            const int eq = f & 15;
            const size_t goff = ((size_t)bb * I_ + (ib + ii)) * E_ + etile * 64 + eq * 4;
            float4 vx = *(const float4*)(x + goff);
            float4 vw = *(const float4*)(Wv + goff);
            *(float4*)&xs[ii][bb][eq * 4] = vx;
            *(float4*)&ws[ii][bb][eq * 4] = vw;
        }
        __syncthreads();

#pragma unroll
        for (int ii = 0; ii < 8; ++ii) {
            float xv[8], wv[8];
#pragma unroll
            for (int bi = 0; bi < 8; ++bi) xv[bi] = xs[ii][b0 + bi][lane];
#pragma unroll
            for (int hj = 0; hj < 8; ++hj) wv[hj] = ws[ii][h0 + hj][lane];
#pragma unroll
            for (int bi = 0; bi < 8; ++bi)
#pragma unroll
                for (int hj = 0; hj < 8; ++hj)
                    acc[bi][hj] = fmaf(xv[bi], wv[hj], acc[bi][hj]);
        }
    }

    // direct partial store: 64 rows x 64 e per wave, coalesced b32 rows.
#pragma unroll
    for (int bi = 0; bi < 8; ++bi)
#pragma unroll
        for (int hj = 0; hj < 8; ++hj) {
            const int row = (b0 + bi) * H_ + h0 + hj;
            part[((size_t)slice * (B_ * H_) + row) * E_ + e] = acc[bi][hj];
        }
}

// ---------------------------------------------------------------------------
// Kernel 2: emb = sum of NSLICE partial slices (float4 lanes). (unchanged)
// ---------------------------------------------------------------------------
__global__ __launch_bounds__(256) void k_emb_reduce(const float4* __restrict__ part,
                                                    float4* __restrict__ emb) {
    const int idx = blockIdx.x * 256 + threadIdx.x;
    const int sl  = (B_ * H_ * E_) / 4;
    float4 s = part[idx];
#pragma unroll
    for (int j = 1; j < NSLICE; ++j) {
        float4 p = part[(size_t)j * sl + idx];
        s.x += p.x; s.y += p.y; s.z += p.z; s.w += p.w;
    }
    emb[idx] = s;
}

// ---------------------------------------------------------------------------
// Kernel 3: K-split GEMM partials (Round-2 rebuild, verified R4).
// out-tile 64r x 64c, k-chunk 64, 4x4 micro, 256 threads.
// Grid (8,4,8) = 256 blocks. XOR quad-swizzled LDS both sides, <=2-way.
// ---------------------------------------------------------------------------
__global__ __launch_bounds__(256) void k_mlp_part(const float* __restrict__ emb,
                                                  const float* __restrict__ W,
                                                  float* __restrict__ part) {
    const int cblk = blockIdx.x;   // 64-col tile, 0..7
    const int rblk = blockIdx.y;   // 64-row tile, 0..3
    const int kch  = blockIdx.z;   // 0..7
    const int k0   = kch * 64;

    __shared__ float As[64][68];   // [r][swizzled k]   17.4 KB
    __shared__ float Ws[64][68];   // [k][swizzled c]   17.4 KB

    const int t = threadIdx.x;

#pragma unroll
    for (int it = 0; it < 4; ++it) {
        const int f = t + it * 256;
        const int r = f >> 4, kq = f & 15;
        float4 v = *(const float4*)(emb + (size_t)(rblk * 64 + r) * E_ + k0 + kq * 4);
        *(float4*)&As[r][((kq ^ (r >> 2)) & 15) * 4] = v;
    }
#pragma unroll
    for (int it = 0; it < 4; ++it) {
        const int f = t + it * 256;
        const int c = f >> 4, kq = f & 15;
        float4 v = *(const float4*)(W + (size_t)(cblk * 64 + c) * E_ + k0 + kq * 4);
        const int pc = (((c >> 2) ^ kq) & 15) * 4 + (c & 3);
        Ws[kq * 4 + 0][pc] = v.x;
        Ws[kq * 4 + 1][pc] = v.y;
        Ws[kq * 4 + 2][pc] = v.z;
        Ws[kq * 4 + 3][pc] = v.w;
    }
    __syncthreads();

    const int tx = t & 15, ty = t >> 4;   // c-quad, r-quad
    const int c0 = tx * 4, r0 = ty * 4;

    float4 acc0 = {0, 0, 0, 0}, acc1 = {0, 0, 0, 0};
    float4 acc2 = {0, 0, 0, 0}, acc3 = {0, 0, 0, 0};

    for (int k = 0; k < 64; k += 4) {
        const int K  = k >> 2;
        const int ac = ((K ^ ty) & 15) * 4;
        const int wc = ((tx ^ K) & 15) * 4;
        float4 a0 = *(const float4*)&As[r0 + 0][ac];
        float4 a1 = *(const float4*)&As[r0 + 1][ac];
        float4 a2 = *(const float4*)&As[r0 + 2][ac];
        float4 a3 = *(const float4*)&As[r0 + 3][ac];
        float4 w0 = *(const float4*)&Ws[k + 0][wc];
        float4 w1 = *(const float4*)&Ws[k + 1][wc];
        float4 w2 = *(const float4*)&Ws[k + 2][wc];
        float4 w3 = *(const float4*)&Ws[k + 3][wc];
#define MLP_STEP(ACC, AV)                                                  \
        ACC.x = fmaf(AV.x, w0.x, fmaf(AV.y, w1.x, fmaf(AV.z, w2.x, fmaf(AV.w, w3.x, ACC.x)))); \
        ACC.y = fmaf(AV.x, w0.y, fmaf(AV.y, w1.y, fmaf(AV.z, w2.y, fmaf(AV.w, w3.y, ACC.y)))); \
        ACC.z = fmaf(AV.x, w0.z, fmaf(AV.y, w1.z, fmaf(AV.z, w2.z, fmaf(AV.w, w3.z, ACC.z)))); \
        ACC.w = fmaf(AV.x, w0.w, fmaf(AV.y, w1.w, fmaf(AV.z, w2.w, fmaf(AV.w, w3.w, ACC.w))));
        MLP_STEP(acc0, a0)
        MLP_STEP(acc1, a1)
        MLP_STEP(acc2, a2)
        MLP_STEP(acc3, a3)
#undef MLP_STEP
    }

    float* dst = part + ((size_t)kch * (B_ * H_) + rblk * 64 + r0) * E_ +
                 cblk * 64 + c0;
    *(float4*)(dst + 0 * E_) = acc0;
    *(float4*)(dst + 1 * E_) = acc1;
    *(float4*)(dst + 2 * E_) = acc2;
    *(float4*)(dst + 3 * E_) = acc3;
}

// ---------------------------------------------------------------------------
// Kernel 4: out = sum of KSPLIT partials + bias. (unchanged)
// ---------------------------------------------------------------------------
__global__ __launch_bounds__(256) void k_out(const float4* __restrict__ part,
                                             const float4* __restrict__ bias,
                                             float4* __restrict__ out) {
    const int idx = blockIdx.x * 256 + threadIdx.x;   // < 32768
    const int sl  = (B_ * H_ * E_) / 4;
    float4 s = part[idx];
#pragma unroll
    for (int j = 1; j < KSPLIT; ++j) {
        float4 p = part[(size_t)j * sl + idx];
        s.x += p.x; s.y += p.y; s.z += p.z; s.w += p.w;
    }
    float4 bv = bias[idx & (E_ / 4 - 1)];
    s.x += bv.x; s.y += bv.y; s.z += bv.z; s.w += bv.w;
    out[idx] = s;
}

extern "C" void kernel_launch(void* const* d_in, const int* in_sizes, int n_in,
                              void* d_out, int out_size, void* d_ws, size_t ws_size,
                              hipStream_t stream) {
    // setup_inputs order: x, W_q, W_k, W_v, mlp_w, mlp_b  (all fp32)
    const float* x     = (const float*)d_in[0];
    const float* W_v   = (const float*)d_in[3];
    const float* mlp_w = (const float*)d_in[4];
    const float* mlp_b = (const float*)d_in[5];
    float* out = (float*)d_out;

    // ws layout: emb partials (16 x 256 x 512 = 8 MB) | emb (512 KB) |
    //            mlp partials (8 x 256 x 512 = 4 MB)
    float* epart = (float*)d_ws;
    float* emb   = epart + (size_t)NSLICE * B_ * H_ * E_;
    float* mpart = emb + (size_t)B_ * H_ * E_;

    dim3 g1(E_ / 64, NSLICE);                      // (8,16) = 128 blocks
    k_emb_part<<<g1, 256, 0, stream>>>(x, W_v, epart);

    k_emb_reduce<<<(B_ * H_ * E_ / 4) / 256, 256, 0, stream>>>(
        (const float4*)epart, (float4*)emb);

    dim3 g3(E_ / 64, (B_ * H_) / 64, KSPLIT);      // (8,4,8) = 256 blocks
    k_mlp_part<<<g3, 256, 0, stream>>>(emb, mlp_w, mpart);

    k_out<<<(B_ * H_ * E_ / 4) / 256, 256, 0, stream>>>(
        (const float4*)mpart, (const float4*)mlp_b, (float4*)out);
}